// Round 1
// baseline (5732.115 us; speedup 1.0000x reference)
//
#include <hip/hip_runtime.h>

// ---------------------------------------------------------------------------
// DummyFairGCN: 3x (GCNConv -> BN(eval) -> ReLU) -> Linear+ReLU -> Linear
// fp32 baseline. Aggregation via per-edge float atomics.
// ---------------------------------------------------------------------------

static inline int cdiv(int a, int b) { return (a + b - 1) / b; }

__global__ __launch_bounds__(256) void k_fill1(float* p, int n) {
    int i = blockIdx.x * 256 + threadIdx.x;
    if (i < n) p[i] = 1.0f;
}

__global__ __launch_bounds__(256) void k_zero4(float4* p, int n4) {
    int i = blockIdx.x * 256 + threadIdx.x;
    if (i < n4) p[i] = float4{0.f, 0.f, 0.f, 0.f};
}

__global__ __launch_bounds__(256) void k_deg(const int* __restrict__ ei, int E, float* deg) {
    int i = blockIdx.x * 256 + threadIdx.x;
    if (i < E) atomicAdd(&deg[ei[E + i]], 1.0f);
}

__global__ __launch_bounds__(256) void k_dinv(float* d, int n) {
    int i = blockIdx.x * 256 + threadIdx.x;
    if (i < n) d[i] = rsqrtf(fmaxf(d[i], 1.0f));
}

// Tiled fp32 GEMM: Y[N x FO](cols col0..col0+FOT) = X[N x K] @ W[K x ldw]
// RB=32 rows/block, FOT=128 cols/block, KC=64 K-chunk staged in LDS.
template <int K, int KC, int FOT, bool BIAS, bool RELU>
__global__ __launch_bounds__(256) void k_gemm(const float* __restrict__ X, int ldx,
                                              const float* __restrict__ W, int ldw,
                                              const float* __restrict__ bias,
                                              float* __restrict__ Y, int ldy, int N) {
    constexpr int RB = 32;
    constexpr int CG = FOT / 4;   // thread groups across columns (32)
    constexpr int RG = 256 / CG;  // thread groups across rows (8)
    constexpr int RPT = RB / RG;  // rows per thread (4)
    __shared__ float ws[KC * FOT];
    __shared__ float xs[RB * (KC + 4)];

    const int tid = threadIdx.x;
    const int tc = tid % CG;
    const int tr = tid / CG;
    const int row0 = blockIdx.x * RB;
    const int col0 = blockIdx.y * FOT;

    float acc[RPT][4];
#pragma unroll
    for (int i = 0; i < RPT; ++i)
#pragma unroll
        for (int j = 0; j < 4; ++j) acc[i][j] = 0.f;

    for (int kb = 0; kb < K; kb += KC) {
        // stage W chunk [KC x FOT]
#pragma unroll
        for (int idx = tid; idx < KC * FOT / 4; idx += 256) {
            int kk = idx / CG;
            int c4 = idx % CG;
            *(float4*)&ws[kk * FOT + c4 * 4] =
                *(const float4*)&W[(size_t)(kb + kk) * ldw + col0 + c4 * 4];
        }
        // stage X chunk [RB x KC] (pad +4 to break bank conflicts)
#pragma unroll
        for (int idx = tid; idx < RB * KC / 4; idx += 256) {
            int r = idx / (KC / 4);
            int k4 = idx % (KC / 4);
            int row = row0 + r;
            float4 v = float4{0.f, 0.f, 0.f, 0.f};
            if (row < N) v = *(const float4*)&X[(size_t)row * ldx + kb + k4 * 4];
            *(float4*)&xs[r * (KC + 4) + k4 * 4] = v;
        }
        __syncthreads();
#pragma unroll 16
        for (int kk = 0; kk < KC; ++kk) {
            float4 wv = *(const float4*)&ws[kk * FOT + tc * 4];
#pragma unroll
            for (int i = 0; i < RPT; ++i) {
                float xv = xs[(tr * RPT + i) * (KC + 4) + kk];
                acc[i][0] += xv * wv.x;
                acc[i][1] += xv * wv.y;
                acc[i][2] += xv * wv.z;
                acc[i][3] += xv * wv.w;
            }
        }
        __syncthreads();
    }

    float4 bv = float4{0.f, 0.f, 0.f, 0.f};
    if (BIAS) bv = *(const float4*)&bias[col0 + tc * 4];
#pragma unroll
    for (int i = 0; i < RPT; ++i) {
        int row = row0 + tr * RPT + i;
        if (row < N) {
            float4 o;
            o.x = acc[i][0] + bv.x;
            o.y = acc[i][1] + bv.y;
            o.z = acc[i][2] + bv.z;
            o.w = acc[i][3] + bv.w;
            if (RELU) {
                o.x = fmaxf(o.x, 0.f);
                o.y = fmaxf(o.y, 0.f);
                o.z = fmaxf(o.z, 0.f);
                o.w = fmaxf(o.w, 0.f);
            }
            *(float4*)&Y[(size_t)row * ldy + col0 + tc * 4] = o;
        }
    }
}

// Edge scatter: agg[dst] += dinv[src]*dinv[dst] * xw[src]; one float4 / thread.
template <int FO>
__global__ __launch_bounds__(256) void k_scatter(const int* __restrict__ ei, int E,
                                                 const float* __restrict__ dinv,
                                                 const float* __restrict__ xw,
                                                 float* __restrict__ agg) {
    constexpr int NP = FO / 4;
    int t = blockIdx.x * 256 + threadIdx.x;
    int e = t / NP;
    if (e >= E) return;
    int c = (t - e * NP) * 4;
    int src = ei[e];
    int dst = ei[E + e];
    float w = dinv[src] * dinv[dst];
    float4 v = *(const float4*)&xw[(size_t)src * FO + c];
    float* a = &agg[(size_t)dst * FO + c];
    atomicAdd(a + 0, v.x * w);
    atomicAdd(a + 1, v.y * w);
    atomicAdd(a + 2, v.z * w);
    atomicAdd(a + 3, v.w * w);
}

// Epilogue: h = relu(bn(agg + dinv^2*xw + conv_b)), in-place over agg allowed.
template <int FO>
__global__ __launch_bounds__(256) void k_epi(const float* __restrict__ agg,
                                             const float* __restrict__ xw,
                                             const float* __restrict__ dinv,
                                             const float* __restrict__ cb,
                                             const float* __restrict__ g,
                                             const float* __restrict__ bb,
                                             const float* __restrict__ m,
                                             const float* __restrict__ vv,
                                             float* __restrict__ h, int N) {
    constexpr int NP = FO / 4;
    int t = blockIdx.x * 256 + threadIdx.x;
    int node = t / NP;
    if (node >= N) return;
    int c = (t - node * NP) * 4;
    float di = dinv[node];
    float s = di * di;
    float4 a = *(const float4*)&agg[(size_t)node * FO + c];
    float4 x = *(const float4*)&xw[(size_t)node * FO + c];
    float4 B = *(const float4*)&cb[c];
    float4 G = *(const float4*)&g[c];
    float4 BB = *(const float4*)&bb[c];
    float4 M = *(const float4*)&m[c];
    float4 V = *(const float4*)&vv[c];
    float4 o;
    o.x = fmaxf((a.x + s * x.x + B.x - M.x) * rsqrtf(V.x + 1e-5f) * G.x + BB.x, 0.f);
    o.y = fmaxf((a.y + s * x.y + B.y - M.y) * rsqrtf(V.y + 1e-5f) * G.y + BB.y, 0.f);
    o.z = fmaxf((a.z + s * x.z + B.z - M.z) * rsqrtf(V.z + 1e-5f) * G.z + BB.z, 0.f);
    o.w = fmaxf((a.w + s * x.w + B.w - M.w) * rsqrtf(V.w + 1e-5f) * G.w + BB.w, 0.f);
    *(float4*)&h[(size_t)node * FO + c] = o;
}

// lin2: Y[N x 40] = X[N x 128] @ W[128 x 40] + b
__global__ __launch_bounds__(256) void k_lin2(const float* __restrict__ X,
                                              const float* __restrict__ W,
                                              const float* __restrict__ b,
                                              float* __restrict__ Y, int N) {
    __shared__ float ws[128 * 40];
    __shared__ float xs[4][128];
    const int tid = threadIdx.x;
    const int row0 = blockIdx.x * 4;
#pragma unroll
    for (int idx = tid; idx < 128 * 40 / 4; idx += 256) {
        *(float4*)&ws[idx * 4] = *(const float4*)&W[idx * 4];
    }
    if (tid < 128) {
        int r = tid >> 5;
        int k4 = tid & 31;
        int row = row0 + r;
        float4 v = float4{0.f, 0.f, 0.f, 0.f};
        if (row < N) v = *(const float4*)&X[(size_t)row * 128 + k4 * 4];
        *(float4*)&xs[r][k4 * 4] = v;
    }
    __syncthreads();
    const int tc = tid & 63;
    const int tr = tid >> 6;
    if (tc < 40) {
        float acc = 0.f;
#pragma unroll
        for (int k = 0; k < 128; ++k) acc += xs[tr][k] * ws[k * 40 + tc];
        int row = row0 + tr;
        if (row < N) Y[(size_t)row * 40 + tc] = acc + b[tc];
    }
}

extern "C" void kernel_launch(void* const* d_in, const int* in_sizes, int n_in,
                              void* d_out, int out_size, void* d_ws, size_t ws_size,
                              hipStream_t stream) {
    const float* x = (const float*)d_in[0];
    const int* ei = (const int*)d_in[1];
    const float* cw1 = (const float*)d_in[2];
    const float* cb1 = (const float*)d_in[3];
    const float* g1 = (const float*)d_in[4];
    const float* bb1 = (const float*)d_in[5];
    const float* m1 = (const float*)d_in[6];
    const float* v1 = (const float*)d_in[7];
    const float* cw2 = (const float*)d_in[8];
    const float* cb2 = (const float*)d_in[9];
    const float* g2 = (const float*)d_in[10];
    const float* bb2 = (const float*)d_in[11];
    const float* m2 = (const float*)d_in[12];
    const float* v2 = (const float*)d_in[13];
    const float* cw3 = (const float*)d_in[14];
    const float* cb3 = (const float*)d_in[15];
    const float* g3 = (const float*)d_in[16];
    const float* bb3 = (const float*)d_in[17];
    const float* m3 = (const float*)d_in[18];
    const float* v3 = (const float*)d_in[19];
    const float* lw1 = (const float*)d_in[20];
    const float* lb1 = (const float*)d_in[21];
    const float* lw2 = (const float*)d_in[22];
    const float* lb2 = (const float*)d_in[23];
    float* out = (float*)d_out;

    const int N = in_sizes[0] / 128;
    const int E = in_sizes[1] / 2;

    char* w = (char*)d_ws;
    float* dinv = (float*)w;
    size_t off = (((size_t)N * 4) + 255) & ~(size_t)255;
    float* P = (float*)(w + off);
    float* Q = P + (size_t)N * 256;

    // degree -> dinv
    k_fill1<<<cdiv(N, 256), 256, 0, stream>>>(dinv, N);
    k_deg<<<cdiv(E, 256), 256, 0, stream>>>(ei, E, dinv);
    k_dinv<<<cdiv(N, 256), 256, 0, stream>>>(dinv, N);

    // ---- conv1: xw = x @ W1 (N x 128) -> Q
    k_gemm<128, 64, 128, false, false>
        <<<dim3(cdiv(N, 32), 1), 256, 0, stream>>>(x, 128, cw1, 128, nullptr, Q, 128, N);
    k_zero4<<<cdiv(N * 32, 256), 256, 0, stream>>>((float4*)P, N * 32);
    k_scatter<128><<<cdiv(E * 32, 256), 256, 0, stream>>>(ei, E, dinv, Q, P);
    k_epi<128><<<cdiv(N * 32, 256), 256, 0, stream>>>(P, Q, dinv, cb1, g1, bb1, m1, v1, P, N);

    // ---- conv2: h1(P) @ W2 -> Q
    k_gemm<128, 64, 128, false, false>
        <<<dim3(cdiv(N, 32), 1), 256, 0, stream>>>(P, 128, cw2, 128, nullptr, Q, 128, N);
    k_zero4<<<cdiv(N * 32, 256), 256, 0, stream>>>((float4*)P, N * 32);
    k_scatter<128><<<cdiv(E * 32, 256), 256, 0, stream>>>(ei, E, dinv, Q, P);
    k_epi<128><<<cdiv(N * 32, 256), 256, 0, stream>>>(P, Q, dinv, cb2, g2, bb2, m2, v2, P, N);

    // ---- conv3: h2(P) @ W3 (N x 256) -> Q
    k_gemm<128, 64, 128, false, false>
        <<<dim3(cdiv(N, 32), 2), 256, 0, stream>>>(P, 128, cw3, 256, nullptr, Q, 256, N);
    k_zero4<<<cdiv(N * 64, 256), 256, 0, stream>>>((float4*)P, N * 64);
    k_scatter<256><<<cdiv(E * 64, 256), 256, 0, stream>>>(ei, E, dinv, Q, P);
    k_epi<256><<<cdiv(N * 64, 256), 256, 0, stream>>>(P, Q, dinv, cb3, g3, bb3, m3, v3, P, N);

    // ---- lin1: relu(h3(P, ld 256) @ lw1 + lb1) -> Q (N x 128)
    k_gemm<256, 64, 128, true, true>
        <<<dim3(cdiv(N, 32), 1), 256, 0, stream>>>(P, 256, lw1, 128, lb1, Q, 128, N);

    // ---- lin2: Q @ lw2 + lb2 -> out (N x 40)
    k_lin2<<<cdiv(N, 4), 256, 0, stream>>>(Q, lw2, lb2, out, N);
}

// Round 2
// 585.442 us; speedup vs baseline: 9.7911x; 9.7911x over previous
//
#include <hip/hip_runtime.h>

// ---------------------------------------------------------------------------
// DummyFairGCN: 3x (GCNConv -> BN(eval) -> ReLU) -> Linear+ReLU -> Linear
// R2: CSR-gather aggregation (no float atomics), fused epilogue.
// ---------------------------------------------------------------------------

static inline int cdiv(int a, int b) { return (a + b - 1) / b; }

__global__ __launch_bounds__(256) void k_zero_int(int* p, int n) {
    int i = blockIdx.x * 256 + threadIdx.x;
    if (i < n) p[i] = 0;
}

__global__ __launch_bounds__(256) void k_deg(const int* __restrict__ ei, int E, int* deg) {
    int i = blockIdx.x * 256 + threadIdx.x;
    if (i < E) atomicAdd(&deg[ei[E + i]], 1);
}

__global__ __launch_bounds__(256) void k_dinv(const int* __restrict__ deg, float* dinv, int n) {
    int i = blockIdx.x * 256 + threadIdx.x;
    if (i < n) dinv[i] = rsqrtf((float)(deg[i] + 1));  // +1 self-loop, always >=1
}

// ---- exclusive scan of deg[N] -> rowptr[N+1] (3-kernel hierarchy) ----
__global__ __launch_bounds__(256) void k_scan1(const int* __restrict__ deg, int* part, int n) {
    __shared__ int s[256];
    int i = blockIdx.x * 256 + threadIdx.x;
    s[threadIdx.x] = (i < n) ? deg[i] : 0;
    __syncthreads();
#pragma unroll
    for (int off = 128; off > 0; off >>= 1) {
        if (threadIdx.x < off) s[threadIdx.x] += s[threadIdx.x + off];
        __syncthreads();
    }
    if (threadIdx.x == 0) part[blockIdx.x] = s[0];
}

__global__ void k_scan2(int* part, int nb) {  // nb <= 1024, single block of 1024
    __shared__ int s[1024];
    int v = (threadIdx.x < nb) ? part[threadIdx.x] : 0;
    s[threadIdx.x] = v;
    __syncthreads();
    for (int off = 1; off < 1024; off <<= 1) {
        int t = (threadIdx.x >= (unsigned)off) ? s[threadIdx.x - off] : 0;
        __syncthreads();
        s[threadIdx.x] += t;
        __syncthreads();
    }
    if (threadIdx.x < nb) part[threadIdx.x] = s[threadIdx.x] - v;  // exclusive
}

__global__ __launch_bounds__(256) void k_scan3(const int* __restrict__ deg,
                                               const int* __restrict__ part,
                                               int* rowptr, int n) {
    __shared__ int s[256];
    int i = blockIdx.x * 256 + threadIdx.x;
    int v = (i < n) ? deg[i] : 0;
    s[threadIdx.x] = v;
    __syncthreads();
    for (int off = 1; off < 256; off <<= 1) {
        int t = (threadIdx.x >= (unsigned)off) ? s[threadIdx.x - off] : 0;
        __syncthreads();
        s[threadIdx.x] += t;
        __syncthreads();
    }
    int excl = part[blockIdx.x] + s[threadIdx.x] - v;
    if (i < n) rowptr[i] = excl;
    if (i == n - 1) rowptr[n] = excl + v;
}

__global__ __launch_bounds__(256) void k_fill_csr(const int* __restrict__ ei, int E,
                                                  const int* __restrict__ rowptr,
                                                  int* cursor, int* csr) {
    int e = blockIdx.x * 256 + threadIdx.x;
    if (e >= E) return;
    int src = ei[e];
    int dst = ei[E + e];
    int p = rowptr[dst] + atomicAdd(&cursor[dst], 1);
    csr[p] = src;
}

// Tiled fp32 GEMM: Y[N x FO](cols col0..col0+FOT) = X[N x K] @ W[K x ldw]
template <int K, int KC, int FOT, bool BIAS, bool RELU>
__global__ __launch_bounds__(256) void k_gemm(const float* __restrict__ X, int ldx,
                                              const float* __restrict__ W, int ldw,
                                              const float* __restrict__ bias,
                                              float* __restrict__ Y, int ldy, int N) {
    constexpr int RB = 32;
    constexpr int CG = FOT / 4;   // 32 thread-groups across columns
    constexpr int RG = 256 / CG;  // 8 across rows
    constexpr int RPT = RB / RG;  // 4 rows per thread
    __shared__ float ws[KC * FOT];
    __shared__ float xs[RB * (KC + 4)];

    const int tid = threadIdx.x;
    const int tc = tid % CG;
    const int tr = tid / CG;
    const int row0 = blockIdx.x * RB;
    const int col0 = blockIdx.y * FOT;

    float acc[RPT][4];
#pragma unroll
    for (int i = 0; i < RPT; ++i)
#pragma unroll
        for (int j = 0; j < 4; ++j) acc[i][j] = 0.f;

    for (int kb = 0; kb < K; kb += KC) {
#pragma unroll
        for (int idx = tid; idx < KC * FOT / 4; idx += 256) {
            int kk = idx / CG;
            int c4 = idx % CG;
            *(float4*)&ws[kk * FOT + c4 * 4] =
                *(const float4*)&W[(size_t)(kb + kk) * ldw + col0 + c4 * 4];
        }
#pragma unroll
        for (int idx = tid; idx < RB * KC / 4; idx += 256) {
            int r = idx / (KC / 4);
            int k4 = idx % (KC / 4);
            int row = row0 + r;
            float4 v = float4{0.f, 0.f, 0.f, 0.f};
            if (row < N) v = *(const float4*)&X[(size_t)row * ldx + kb + k4 * 4];
            *(float4*)&xs[r * (KC + 4) + k4 * 4] = v;
        }
        __syncthreads();
#pragma unroll 16
        for (int kk = 0; kk < KC; ++kk) {
            float4 wv = *(const float4*)&ws[kk * FOT + tc * 4];
#pragma unroll
            for (int i = 0; i < RPT; ++i) {
                float xv = xs[(tr * RPT + i) * (KC + 4) + kk];
                acc[i][0] += xv * wv.x;
                acc[i][1] += xv * wv.y;
                acc[i][2] += xv * wv.z;
                acc[i][3] += xv * wv.w;
            }
        }
        __syncthreads();
    }

    float4 bv = float4{0.f, 0.f, 0.f, 0.f};
    if (BIAS) bv = *(const float4*)&bias[col0 + tc * 4];
#pragma unroll
    for (int i = 0; i < RPT; ++i) {
        int row = row0 + tr * RPT + i;
        if (row < N) {
            float4 o;
            o.x = acc[i][0] + bv.x;
            o.y = acc[i][1] + bv.y;
            o.z = acc[i][2] + bv.z;
            o.w = acc[i][3] + bv.w;
            if (RELU) {
                o.x = fmaxf(o.x, 0.f);
                o.y = fmaxf(o.y, 0.f);
                o.z = fmaxf(o.z, 0.f);
                o.w = fmaxf(o.w, 0.f);
            }
            *(float4*)&Y[(size_t)row * ldy + col0 + tc * 4] = o;
        }
    }
}

// Fused gather + self-loop + bias + BN + ReLU.
// One thread = one float4 column chunk of one dst node.
template <int FO>
__global__ __launch_bounds__(256) void k_gather_epi(const int* __restrict__ rowptr,
                                                    const int* __restrict__ csr,
                                                    const float* __restrict__ dinv,
                                                    const float* __restrict__ xw,
                                                    const float* __restrict__ cb,
                                                    const float* __restrict__ g,
                                                    const float* __restrict__ bb,
                                                    const float* __restrict__ m,
                                                    const float* __restrict__ vv,
                                                    float* __restrict__ h, int N) {
    constexpr int NP = FO / 4;
    int t = blockIdx.x * 256 + threadIdx.x;
    int node = t / NP;
    if (node >= N) return;
    int c = (t - node * NP) * 4;
    float di = dinv[node];
    float s = di * di;
    float4 xv = *(const float4*)&xw[(size_t)node * FO + c];
    float ax = s * xv.x, ay = s * xv.y, az = s * xv.z, aw = s * xv.w;
    int p0 = rowptr[node], p1 = rowptr[node + 1];
    for (int p = p0; p < p1; ++p) {
        int src = csr[p];                 // broadcast within the node's group
        float w = di * dinv[src];
        float4 v = *(const float4*)&xw[(size_t)src * FO + c];
        ax += w * v.x;
        ay += w * v.y;
        az += w * v.z;
        aw += w * v.w;
    }
    float4 B = *(const float4*)&cb[c];
    float4 G = *(const float4*)&g[c];
    float4 BB = *(const float4*)&bb[c];
    float4 M = *(const float4*)&m[c];
    float4 V = *(const float4*)&vv[c];
    float4 o;
    o.x = fmaxf((ax + B.x - M.x) * rsqrtf(V.x + 1e-5f) * G.x + BB.x, 0.f);
    o.y = fmaxf((ay + B.y - M.y) * rsqrtf(V.y + 1e-5f) * G.y + BB.y, 0.f);
    o.z = fmaxf((az + B.z - M.z) * rsqrtf(V.z + 1e-5f) * G.z + BB.z, 0.f);
    o.w = fmaxf((aw + B.w - M.w) * rsqrtf(V.w + 1e-5f) * G.w + BB.w, 0.f);
    *(float4*)&h[(size_t)node * FO + c] = o;
}

// lin2: Y[N x 40] = X[N x 128] @ W[128 x 40] + b
__global__ __launch_bounds__(256) void k_lin2(const float* __restrict__ X,
                                              const float* __restrict__ W,
                                              const float* __restrict__ b,
                                              float* __restrict__ Y, int N) {
    __shared__ float ws[128 * 40];
    __shared__ float xs[4][128];
    const int tid = threadIdx.x;
    const int row0 = blockIdx.x * 4;
#pragma unroll
    for (int idx = tid; idx < 128 * 40 / 4; idx += 256) {
        *(float4*)&ws[idx * 4] = *(const float4*)&W[idx * 4];
    }
    if (tid < 128) {
        int r = tid >> 5;
        int k4 = tid & 31;
        int row = row0 + r;
        float4 v = float4{0.f, 0.f, 0.f, 0.f};
        if (row < N) v = *(const float4*)&X[(size_t)row * 128 + k4 * 4];
        *(float4*)&xs[r][k4 * 4] = v;
    }
    __syncthreads();
    const int tc = tid & 63;
    const int tr = tid >> 6;
    if (tc < 40) {
        float acc = 0.f;
#pragma unroll
        for (int k = 0; k < 128; ++k) acc += xs[tr][k] * ws[k * 40 + tc];
        int row = row0 + tr;
        if (row < N) Y[(size_t)row * 40 + tc] = acc + b[tc];
    }
}

extern "C" void kernel_launch(void* const* d_in, const int* in_sizes, int n_in,
                              void* d_out, int out_size, void* d_ws, size_t ws_size,
                              hipStream_t stream) {
    const float* x = (const float*)d_in[0];
    const int* ei = (const int*)d_in[1];
    const float* cw1 = (const float*)d_in[2];
    const float* cb1 = (const float*)d_in[3];
    const float* g1 = (const float*)d_in[4];
    const float* bb1 = (const float*)d_in[5];
    const float* m1 = (const float*)d_in[6];
    const float* v1 = (const float*)d_in[7];
    const float* cw2 = (const float*)d_in[8];
    const float* cb2 = (const float*)d_in[9];
    const float* g2 = (const float*)d_in[10];
    const float* bb2 = (const float*)d_in[11];
    const float* m2 = (const float*)d_in[12];
    const float* v2 = (const float*)d_in[13];
    const float* cw3 = (const float*)d_in[14];
    const float* cb3 = (const float*)d_in[15];
    const float* g3 = (const float*)d_in[16];
    const float* bb3 = (const float*)d_in[17];
    const float* m3 = (const float*)d_in[18];
    const float* v3 = (const float*)d_in[19];
    const float* lw1 = (const float*)d_in[20];
    const float* lb1 = (const float*)d_in[21];
    const float* lw2 = (const float*)d_in[22];
    const float* lb2 = (const float*)d_in[23];
    float* out = (float*)d_out;

    const int N = in_sizes[0] / 128;
    const int E = in_sizes[1] / 2;

    auto al = [](size_t x) { return (x + 255) & ~(size_t)255; };
    char* w = (char*)d_ws;
    size_t o = 0;
    float* dinv = (float*)(w + o); o = al(o + (size_t)N * 4);
    int* deg    = (int*)(w + o);   o = al(o + (size_t)N * 4);   // reused as cursor
    int* rowptr = (int*)(w + o);   o = al(o + (size_t)(N + 1) * 4);
    int* part   = (int*)(w + o);   o = al(o + 1024 * 4);
    int* csr    = (int*)(w + o);   o = al(o + (size_t)E * 4);
    float* P    = (float*)(w + o); o = al(o + (size_t)N * 256 * 4);
    float* Q    = (float*)(w + o); o = al(o + (size_t)N * 256 * 4);

    const int nb = cdiv(N, 256);

    // ---- CSR build (once; edge_index constant across layers) ----
    k_zero_int<<<cdiv(N, 256), 256, 0, stream>>>(deg, N);
    k_deg<<<cdiv(E, 256), 256, 0, stream>>>(ei, E, deg);
    k_dinv<<<cdiv(N, 256), 256, 0, stream>>>(deg, dinv, N);
    k_scan1<<<nb, 256, 0, stream>>>(deg, part, N);
    k_scan2<<<1, 1024, 0, stream>>>(part, nb);
    k_scan3<<<nb, 256, 0, stream>>>(deg, part, rowptr, N);
    k_zero_int<<<cdiv(N, 256), 256, 0, stream>>>(deg, N);  // cursor
    k_fill_csr<<<cdiv(E, 256), 256, 0, stream>>>(ei, E, rowptr, deg, csr);

    // ---- conv1: Q = x @ W1 (N x 128); P = relu(bn(agg(Q)+b1))
    k_gemm<128, 64, 128, false, false>
        <<<dim3(cdiv(N, 32), 1), 256, 0, stream>>>(x, 128, cw1, 128, nullptr, Q, 128, N);
    k_gather_epi<128><<<cdiv(N * 32, 256), 256, 0, stream>>>(rowptr, csr, dinv, Q, cb1, g1,
                                                             bb1, m1, v1, P, N);

    // ---- conv2
    k_gemm<128, 64, 128, false, false>
        <<<dim3(cdiv(N, 32), 1), 256, 0, stream>>>(P, 128, cw2, 128, nullptr, Q, 128, N);
    k_gather_epi<128><<<cdiv(N * 32, 256), 256, 0, stream>>>(rowptr, csr, dinv, Q, cb2, g2,
                                                             bb2, m2, v2, P, N);

    // ---- conv3 (out width 256)
    k_gemm<128, 64, 128, false, false>
        <<<dim3(cdiv(N, 32), 2), 256, 0, stream>>>(P, 128, cw3, 256, nullptr, Q, 256, N);
    k_gather_epi<256><<<cdiv(N * 64, 256), 256, 0, stream>>>(rowptr, csr, dinv, Q, cb3, g3,
                                                             bb3, m3, v3, P, N);

    // ---- lin1: Q = relu(P[N x 256] @ lw1 + lb1)
    k_gemm<256, 64, 128, true, true>
        <<<dim3(cdiv(N, 32), 1), 256, 0, stream>>>(P, 256, lw1, 128, lb1, Q, 128, N);

    // ---- lin2: out = Q @ lw2 + lb2
    k_lin2<<<cdiv(N, 4), 256, 0, stream>>>(Q, lw2, lb2, out, N);
}

// Round 3
// 432.572 us; speedup vs baseline: 13.2512x; 1.3534x over previous
//
#include <hip/hip_runtime.h>
#include <hip/hip_fp16.h>

// ---------------------------------------------------------------------------
// DummyFairGCN R3: aggregate-first (agg commutes with dense W), fp16 gather
// operand, 4-edge-unrolled CSR gather, BN+ReLU fused into GEMM epilogues.
// Pipeline:
//   x ->f2h-> XH; gather(XH)->G; GEMM+BN+ReLU(G,W1)->XH(h1);
//   gather->G; GEMM+BN+ReLU(G,W2)->XH(h2);
//   gather->G; GEMM+BN+ReLU(G,W3,256)->H3(f32);
//   lin1+ReLU(H3)->Z; lin2(Z)->out
// ---------------------------------------------------------------------------

static inline int cdiv(int a, int b) { return (a + b - 1) / b; }

__global__ __launch_bounds__(256) void k_zero_int(int* p, int n) {
    int i = blockIdx.x * 256 + threadIdx.x;
    if (i < n) p[i] = 0;
}

__global__ __launch_bounds__(256) void k_deg(const int* __restrict__ ei, int E, int* deg) {
    int i = blockIdx.x * 256 + threadIdx.x;
    if (i < E) atomicAdd(&deg[ei[E + i]], 1);
}

__global__ __launch_bounds__(256) void k_dinv(const int* __restrict__ deg, float* dinv, int n) {
    int i = blockIdx.x * 256 + threadIdx.x;
    if (i < n) dinv[i] = rsqrtf((float)(deg[i] + 1));  // +1 self-loop
}

// ---- exclusive scan of deg[N] -> rowptr[N+1] ----
__global__ __launch_bounds__(256) void k_scan1(const int* __restrict__ deg, int* part, int n) {
    __shared__ int s[256];
    int i = blockIdx.x * 256 + threadIdx.x;
    s[threadIdx.x] = (i < n) ? deg[i] : 0;
    __syncthreads();
#pragma unroll
    for (int off = 128; off > 0; off >>= 1) {
        if (threadIdx.x < off) s[threadIdx.x] += s[threadIdx.x + off];
        __syncthreads();
    }
    if (threadIdx.x == 0) part[blockIdx.x] = s[0];
}

__global__ void k_scan2(int* part, int nb) {  // nb <= 1024
    __shared__ int s[1024];
    int v = (threadIdx.x < nb) ? part[threadIdx.x] : 0;
    s[threadIdx.x] = v;
    __syncthreads();
    for (int off = 1; off < 1024; off <<= 1) {
        int t = (threadIdx.x >= (unsigned)off) ? s[threadIdx.x - off] : 0;
        __syncthreads();
        s[threadIdx.x] += t;
        __syncthreads();
    }
    if (threadIdx.x < nb) part[threadIdx.x] = s[threadIdx.x] - v;  // exclusive
}

__global__ __launch_bounds__(256) void k_scan3(const int* __restrict__ deg,
                                               const int* __restrict__ part,
                                               int* rowptr, int n) {
    __shared__ int s[256];
    int i = blockIdx.x * 256 + threadIdx.x;
    int v = (i < n) ? deg[i] : 0;
    s[threadIdx.x] = v;
    __syncthreads();
    for (int off = 1; off < 256; off <<= 1) {
        int t = (threadIdx.x >= (unsigned)off) ? s[threadIdx.x - off] : 0;
        __syncthreads();
        s[threadIdx.x] += t;
        __syncthreads();
    }
    int excl = part[blockIdx.x] + s[threadIdx.x] - v;
    if (i < n) rowptr[i] = excl;
    if (i == n - 1) rowptr[n] = excl + v;
}

__global__ __launch_bounds__(256) void k_fill_csr(const int* __restrict__ ei, int E,
                                                  const int* __restrict__ rowptr,
                                                  int* cursor, int* csr) {
    int e = blockIdx.x * 256 + threadIdx.x;
    if (e >= E) return;
    int src = ei[e];
    int dst = ei[E + e];
    int p = rowptr[dst] + atomicAdd(&cursor[dst], 1);
    csr[p] = src;
}

__global__ __launch_bounds__(256) void k_f2h(const float* __restrict__ x, __half* __restrict__ y,
                                             int n4) {
    int i = blockIdx.x * 256 + threadIdx.x;
    if (i >= n4) return;
    float4 v = ((const float4*)x)[i];
    __half h[4] = {__float2half_rn(v.x), __float2half_rn(v.y), __float2half_rn(v.z),
                   __float2half_rn(v.w)};
    ((uint2*)y)[i] = *(uint2*)h;
}

__device__ inline void unpack8(uint4 v, float* f) {
    __half2* h = (__half2*)&v;
#pragma unroll
    for (int i = 0; i < 4; ++i) {
        float2 t = __half22float2(h[i]);
        f[2 * i] = t.x;
        f[2 * i + 1] = t.y;
    }
}

// CSR gather over 128-wide fp16 rows: G[node] = dinv^2*xh[node] + sum w*xh[src]
// 16 lanes per node, 16B (8 halves) per lane, 4-edge unroll for MLP.
__global__ __launch_bounds__(256) void k_gather128(const int* __restrict__ rowptr,
                                                   const int* __restrict__ csr,
                                                   const float* __restrict__ dinv,
                                                   const __half* __restrict__ xh,
                                                   float* __restrict__ G, int N) {
    int t = blockIdx.x * 256 + threadIdx.x;
    int node = t >> 4;
    if (node >= N) return;
    int lane = t & 15;
    const uint4* xb = (const uint4*)xh;  // 16 uint4 per row
    float di = dinv[node];
    float acc[8];
    {
        uint4 v = xb[(size_t)node * 16 + lane];
        float f[8];
        unpack8(v, f);
        float s = di * di;
#pragma unroll
        for (int j = 0; j < 8; ++j) acc[j] = s * f[j];
    }
    int p0 = rowptr[node], p1 = rowptr[node + 1];
    int p = p0;
    for (; p + 4 <= p1; p += 4) {
        int s0 = csr[p], s1 = csr[p + 1], s2 = csr[p + 2], s3 = csr[p + 3];
        float w0 = di * dinv[s0], w1 = di * dinv[s1], w2 = di * dinv[s2], w3 = di * dinv[s3];
        uint4 v0 = xb[(size_t)s0 * 16 + lane];
        uint4 v1 = xb[(size_t)s1 * 16 + lane];
        uint4 v2 = xb[(size_t)s2 * 16 + lane];
        uint4 v3 = xb[(size_t)s3 * 16 + lane];
        float f0[8], f1[8], f2[8], f3[8];
        unpack8(v0, f0);
        unpack8(v1, f1);
        unpack8(v2, f2);
        unpack8(v3, f3);
#pragma unroll
        for (int j = 0; j < 8; ++j)
            acc[j] += w0 * f0[j] + w1 * f1[j] + w2 * f2[j] + w3 * f3[j];
    }
    for (; p < p1; ++p) {
        int src = csr[p];
        float w = di * dinv[src];
        uint4 v = xb[(size_t)src * 16 + lane];
        float f[8];
        unpack8(v, f);
#pragma unroll
        for (int j = 0; j < 8; ++j) acc[j] += w * f[j];
    }
    float* gp = &G[(size_t)node * 128 + lane * 8];
    *(float4*)gp = float4{acc[0], acc[1], acc[2], acc[3]};
    *(float4*)(gp + 4) = float4{acc[4], acc[5], acc[6], acc[7]};
}

// Tiled fp32 GEMM with fused BN(eval)+ReLU epilogue; OT = __half or float.
// Y[N x *](cols col0..col0+128) = bnrelu(X[N x K] @ W[K x ldw] + cb)
template <int K, typename OT>
__global__ __launch_bounds__(256) void k_gemm_bn(const float* __restrict__ X, int ldx,
                                                 const float* __restrict__ W, int ldw,
                                                 const float* __restrict__ cb,
                                                 const float* __restrict__ g,
                                                 const float* __restrict__ bb,
                                                 const float* __restrict__ m,
                                                 const float* __restrict__ vv,
                                                 OT* __restrict__ Y, int ldy, int N) {
    constexpr int KC = 64;
    constexpr int RB = 32;
    constexpr int CG = 32;  // thread-groups across 128 cols
    constexpr int RPT = 4;
    __shared__ float ws[KC * 128];
    __shared__ float xs[RB * (KC + 4)];

    const int tid = threadIdx.x;
    const int tc = tid % CG;
    const int tr = tid / CG;
    const int row0 = blockIdx.x * RB;
    const int col0 = blockIdx.y * 128;

    float acc[RPT][4];
#pragma unroll
    for (int i = 0; i < RPT; ++i)
#pragma unroll
        for (int j = 0; j < 4; ++j) acc[i][j] = 0.f;

    for (int kb = 0; kb < K; kb += KC) {
#pragma unroll
        for (int idx = tid; idx < KC * 128 / 4; idx += 256) {
            int kk = idx / CG;
            int c4 = idx % CG;
            *(float4*)&ws[kk * 128 + c4 * 4] =
                *(const float4*)&W[(size_t)(kb + kk) * ldw + col0 + c4 * 4];
        }
#pragma unroll
        for (int idx = tid; idx < RB * KC / 4; idx += 256) {
            int r = idx / (KC / 4);
            int k4 = idx % (KC / 4);
            int row = row0 + r;
            float4 v = float4{0.f, 0.f, 0.f, 0.f};
            if (row < N) v = *(const float4*)&X[(size_t)row * ldx + kb + k4 * 4];
            *(float4*)&xs[r * (KC + 4) + k4 * 4] = v;
        }
        __syncthreads();
#pragma unroll 16
        for (int kk = 0; kk < KC; ++kk) {
            float4 wv = *(const float4*)&ws[kk * 128 + tc * 4];
#pragma unroll
            for (int i = 0; i < RPT; ++i) {
                float xv = xs[(tr * RPT + i) * (KC + 4) + kk];
                acc[i][0] += xv * wv.x;
                acc[i][1] += xv * wv.y;
                acc[i][2] += xv * wv.z;
                acc[i][3] += xv * wv.w;
            }
        }
        __syncthreads();
    }

    float4 B = *(const float4*)&cb[col0 + tc * 4];
    float4 G4 = *(const float4*)&g[col0 + tc * 4];
    float4 BB = *(const float4*)&bb[col0 + tc * 4];
    float4 M = *(const float4*)&m[col0 + tc * 4];
    float4 V = *(const float4*)&vv[col0 + tc * 4];
    float4 sc;  // scale = g*rsqrt(v+eps); shift = bb - (m-cb)*scale
    sc.x = G4.x * rsqrtf(V.x + 1e-5f);
    sc.y = G4.y * rsqrtf(V.y + 1e-5f);
    sc.z = G4.z * rsqrtf(V.z + 1e-5f);
    sc.w = G4.w * rsqrtf(V.w + 1e-5f);
    float4 sh;
    sh.x = BB.x + (B.x - M.x) * sc.x;
    sh.y = BB.y + (B.y - M.y) * sc.y;
    sh.z = BB.z + (B.z - M.z) * sc.z;
    sh.w = BB.w + (B.w - M.w) * sc.w;

#pragma unroll
    for (int i = 0; i < RPT; ++i) {
        int row = row0 + tr * RPT + i;
        if (row < N) {
            float o[4];
            o[0] = fmaxf(acc[i][0] * sc.x + sh.x, 0.f);
            o[1] = fmaxf(acc[i][1] * sc.y + sh.y, 0.f);
            o[2] = fmaxf(acc[i][2] * sc.z + sh.z, 0.f);
            o[3] = fmaxf(acc[i][3] * sc.w + sh.w, 0.f);
            OT* yp = &Y[(size_t)row * ldy + col0 + tc * 4];
            if constexpr (sizeof(OT) == 2) {
                __half h[4] = {__float2half_rn(o[0]), __float2half_rn(o[1]),
                               __float2half_rn(o[2]), __float2half_rn(o[3])};
                *(uint2*)yp = *(uint2*)h;
            } else {
                *(float4*)yp = float4{o[0], o[1], o[2], o[3]};
            }
        }
    }
}

// Plain GEMM + bias (+ReLU): Y[N x 128] = X[N x K] @ W + b
template <int K, bool RELU>
__global__ __launch_bounds__(256) void k_gemm(const float* __restrict__ X, int ldx,
                                              const float* __restrict__ W, int ldw,
                                              const float* __restrict__ bias,
                                              float* __restrict__ Y, int ldy, int N) {
    constexpr int KC = 64;
    constexpr int RB = 32;
    constexpr int CG = 32;
    constexpr int RPT = 4;
    __shared__ float ws[KC * 128];
    __shared__ float xs[RB * (KC + 4)];

    const int tid = threadIdx.x;
    const int tc = tid % CG;
    const int tr = tid / CG;
    const int row0 = blockIdx.x * RB;

    float acc[RPT][4];
#pragma unroll
    for (int i = 0; i < RPT; ++i)
#pragma unroll
        for (int j = 0; j < 4; ++j) acc[i][j] = 0.f;

    for (int kb = 0; kb < K; kb += KC) {
#pragma unroll
        for (int idx = tid; idx < KC * 128 / 4; idx += 256) {
            int kk = idx / CG;
            int c4 = idx % CG;
            *(float4*)&ws[kk * 128 + c4 * 4] =
                *(const float4*)&W[(size_t)(kb + kk) * ldw + c4 * 4];
        }
#pragma unroll
        for (int idx = tid; idx < RB * KC / 4; idx += 256) {
            int r = idx / (KC / 4);
            int k4 = idx % (KC / 4);
            int row = row0 + r;
            float4 v = float4{0.f, 0.f, 0.f, 0.f};
            if (row < N) v = *(const float4*)&X[(size_t)row * ldx + kb + k4 * 4];
            *(float4*)&xs[r * (KC + 4) + k4 * 4] = v;
        }
        __syncthreads();
#pragma unroll 16
        for (int kk = 0; kk < KC; ++kk) {
            float4 wv = *(const float4*)&ws[kk * 128 + tc * 4];
#pragma unroll
            for (int i = 0; i < RPT; ++i) {
                float xv = xs[(tr * RPT + i) * (KC + 4) + kk];
                acc[i][0] += xv * wv.x;
                acc[i][1] += xv * wv.y;
                acc[i][2] += xv * wv.z;
                acc[i][3] += xv * wv.w;
            }
        }
        __syncthreads();
    }

    float4 bv = *(const float4*)&bias[tc * 4];
#pragma unroll
    for (int i = 0; i < RPT; ++i) {
        int row = row0 + tr * RPT + i;
        if (row < N) {
            float4 o;
            o.x = acc[i][0] + bv.x;
            o.y = acc[i][1] + bv.y;
            o.z = acc[i][2] + bv.z;
            o.w = acc[i][3] + bv.w;
            if (RELU) {
                o.x = fmaxf(o.x, 0.f);
                o.y = fmaxf(o.y, 0.f);
                o.z = fmaxf(o.z, 0.f);
                o.w = fmaxf(o.w, 0.f);
            }
            *(float4*)&Y[(size_t)row * ldy + tc * 4] = o;
        }
    }
}

// lin2: Y[N x 40] = X[N x 128] @ W[128 x 40] + b
__global__ __launch_bounds__(256) void k_lin2(const float* __restrict__ X,
                                              const float* __restrict__ W,
                                              const float* __restrict__ b,
                                              float* __restrict__ Y, int N) {
    __shared__ float ws[128 * 40];
    __shared__ float xs[4][128];
    const int tid = threadIdx.x;
    const int row0 = blockIdx.x * 4;
#pragma unroll
    for (int idx = tid; idx < 128 * 40 / 4; idx += 256) {
        *(float4*)&ws[idx * 4] = *(const float4*)&W[idx * 4];
    }
    if (tid < 128) {
        int r = tid >> 5;
        int k4 = tid & 31;
        int row = row0 + r;
        float4 v = float4{0.f, 0.f, 0.f, 0.f};
        if (row < N) v = *(const float4*)&X[(size_t)row * 128 + k4 * 4];
        *(float4*)&xs[r][k4 * 4] = v;
    }
    __syncthreads();
    const int tc = tid & 63;
    const int tr = tid >> 6;
    if (tc < 40) {
        float acc = 0.f;
#pragma unroll
        for (int k = 0; k < 128; ++k) acc += xs[tr][k] * ws[k * 40 + tc];
        int row = row0 + tr;
        if (row < N) Y[(size_t)row * 40 + tc] = acc + b[tc];
    }
}

extern "C" void kernel_launch(void* const* d_in, const int* in_sizes, int n_in,
                              void* d_out, int out_size, void* d_ws, size_t ws_size,
                              hipStream_t stream) {
    const float* x = (const float*)d_in[0];
    const int* ei = (const int*)d_in[1];
    const float* cw1 = (const float*)d_in[2];
    const float* cb1 = (const float*)d_in[3];
    const float* g1 = (const float*)d_in[4];
    const float* bb1 = (const float*)d_in[5];
    const float* m1 = (const float*)d_in[6];
    const float* v1 = (const float*)d_in[7];
    const float* cw2 = (const float*)d_in[8];
    const float* cb2 = (const float*)d_in[9];
    const float* g2 = (const float*)d_in[10];
    const float* bb2 = (const float*)d_in[11];
    const float* m2 = (const float*)d_in[12];
    const float* v2 = (const float*)d_in[13];
    const float* cw3 = (const float*)d_in[14];
    const float* cb3 = (const float*)d_in[15];
    const float* g3 = (const float*)d_in[16];
    const float* bb3 = (const float*)d_in[17];
    const float* m3 = (const float*)d_in[18];
    const float* v3 = (const float*)d_in[19];
    const float* lw1 = (const float*)d_in[20];
    const float* lb1 = (const float*)d_in[21];
    const float* lw2 = (const float*)d_in[22];
    const float* lb2 = (const float*)d_in[23];
    float* out = (float*)d_out;

    const int N = in_sizes[0] / 128;
    const int E = in_sizes[1] / 2;

    auto al = [](size_t v) { return (v + 255) & ~(size_t)255; };
    char* w = (char*)d_ws;
    size_t o = 0;
    float* dinv = (float*)(w + o); o = al(o + (size_t)N * 4);
    int* deg    = (int*)(w + o);   o = al(o + (size_t)N * 4);   // reused as cursor
    int* rowptr = (int*)(w + o);   o = al(o + (size_t)(N + 1) * 4);
    int* part   = (int*)(w + o);   o = al(o + 1024 * 4);
    int* csr    = (int*)(w + o);   o = al(o + (size_t)E * 4);
    __half* XH  = (__half*)(w + o); o = al(o + (size_t)N * 128 * 2);  // x16/h1/h2
    float* G    = (float*)(w + o);  o = al(o + (size_t)N * 128 * 4);  // agg out; later Z
    float* H3   = (float*)(w + o);  o = al(o + (size_t)N * 256 * 4);
    float* Z = G;  // lin1 output overlays G (dead after conv3 GEMM)

    const int nb = cdiv(N, 256);

    // ---- CSR build ----
    k_zero_int<<<cdiv(N, 256), 256, 0, stream>>>(deg, N);
    k_deg<<<cdiv(E, 256), 256, 0, stream>>>(ei, E, deg);
    k_dinv<<<cdiv(N, 256), 256, 0, stream>>>(deg, dinv, N);
    k_scan1<<<nb, 256, 0, stream>>>(deg, part, N);
    k_scan2<<<1, 1024, 0, stream>>>(part, nb);
    k_scan3<<<nb, 256, 0, stream>>>(deg, part, rowptr, N);
    k_zero_int<<<cdiv(N, 256), 256, 0, stream>>>(deg, N);  // cursor
    k_fill_csr<<<cdiv(E, 256), 256, 0, stream>>>(ei, E, rowptr, deg, csr);

    // ---- x -> fp16 ----
    k_f2h<<<cdiv(N * 32, 256), 256, 0, stream>>>(x, XH, N * 32);

    // ---- conv1: G = agg(x16); h1 = bnrelu(G@W1) -> XH
    k_gather128<<<cdiv(N, 16), 256, 0, stream>>>(rowptr, csr, dinv, XH, G, N);
    k_gemm_bn<128, __half><<<dim3(cdiv(N, 32), 1), 256, 0, stream>>>(
        G, 128, cw1, 128, cb1, g1, bb1, m1, v1, XH, 128, N);

    // ---- conv2
    k_gather128<<<cdiv(N, 16), 256, 0, stream>>>(rowptr, csr, dinv, XH, G, N);
    k_gemm_bn<128, __half><<<dim3(cdiv(N, 32), 1), 256, 0, stream>>>(
        G, 128, cw2, 128, cb2, g2, bb2, m2, v2, XH, 128, N);

    // ---- conv3 (out 256, fp32 for lin1)
    k_gather128<<<cdiv(N, 16), 256, 0, stream>>>(rowptr, csr, dinv, XH, G, N);
    k_gemm_bn<128, float><<<dim3(cdiv(N, 32), 2), 256, 0, stream>>>(
        G, 128, cw3, 256, cb3, g3, bb3, m3, v3, H3, 256, N);

    // ---- lin1: Z = relu(H3 @ lw1 + lb1)
    k_gemm<256, true><<<dim3(cdiv(N, 32), 1), 256, 0, stream>>>(H3, 256, lw1, 128, lb1, Z, 128, N);

    // ---- lin2: out = Z @ lw2 + lb2
    k_lin2<<<cdiv(N, 4), 256, 0, stream>>>(Z, lw2, lb2, out, N);
}

// Round 4
// 310.738 us; speedup vs baseline: 18.4468x; 1.3921x over previous
//
#include <hip/hip_runtime.h>
#include <hip/hip_fp16.h>

// ---------------------------------------------------------------------------
// DummyFairGCN R4: MFMA fp16 GEMMs (fp32 accum), fp16 gather, aggregate-first.
// Pipeline:
//   x->f2h->XH; W->Wt fp16 (transposed) per layer;
//   3x [ gather128(XH)->GH ; mfma_gemm+BN+ReLU(GH,Wt)->XH/H3h ]
//   mfma_gemm+bias+ReLU(H3h,Wt4)->Z(f32); k_lin2(Z)->out
// ---------------------------------------------------------------------------

typedef _Float16 f16x8 __attribute__((ext_vector_type(8)));
typedef float f32x4 __attribute__((ext_vector_type(4)));

static inline int cdiv(int a, int b) { return (a + b - 1) / b; }

__global__ __launch_bounds__(256) void k_zero_int(int* p, int n) {
    int i = blockIdx.x * 256 + threadIdx.x;
    if (i < n) p[i] = 0;
}

__global__ __launch_bounds__(256) void k_deg(const int* __restrict__ ei, int E, int* deg) {
    int i = blockIdx.x * 256 + threadIdx.x;
    if (i < E) atomicAdd(&deg[ei[E + i]], 1);
}

__global__ __launch_bounds__(256) void k_dinv(const int* __restrict__ deg, float* dinv, int n) {
    int i = blockIdx.x * 256 + threadIdx.x;
    if (i < n) dinv[i] = rsqrtf((float)(deg[i] + 1));  // +1 self-loop
}

// ---- exclusive scan of deg[N] -> rowptr[N+1] ----
__global__ __launch_bounds__(256) void k_scan1(const int* __restrict__ deg, int* part, int n) {
    __shared__ int s[256];
    int i = blockIdx.x * 256 + threadIdx.x;
    s[threadIdx.x] = (i < n) ? deg[i] : 0;
    __syncthreads();
#pragma unroll
    for (int off = 128; off > 0; off >>= 1) {
        if (threadIdx.x < off) s[threadIdx.x] += s[threadIdx.x + off];
        __syncthreads();
    }
    if (threadIdx.x == 0) part[blockIdx.x] = s[0];
}

__global__ void k_scan2(int* part, int nb) {  // nb <= 1024
    __shared__ int s[1024];
    int v = (threadIdx.x < nb) ? part[threadIdx.x] : 0;
    s[threadIdx.x] = v;
    __syncthreads();
    for (int off = 1; off < 1024; off <<= 1) {
        int t = (threadIdx.x >= (unsigned)off) ? s[threadIdx.x - off] : 0;
        __syncthreads();
        s[threadIdx.x] += t;
        __syncthreads();
    }
    if (threadIdx.x < nb) part[threadIdx.x] = s[threadIdx.x] - v;  // exclusive
}

__global__ __launch_bounds__(256) void k_scan3(const int* __restrict__ deg,
                                               const int* __restrict__ part,
                                               int* rowptr, int n) {
    __shared__ int s[256];
    int i = blockIdx.x * 256 + threadIdx.x;
    int v = (i < n) ? deg[i] : 0;
    s[threadIdx.x] = v;
    __syncthreads();
    for (int off = 1; off < 256; off <<= 1) {
        int t = (threadIdx.x >= (unsigned)off) ? s[threadIdx.x - off] : 0;
        __syncthreads();
        s[threadIdx.x] += t;
        __syncthreads();
    }
    int excl = part[blockIdx.x] + s[threadIdx.x] - v;
    if (i < n) rowptr[i] = excl;
    if (i == n - 1) rowptr[n] = excl + v;
}

__global__ __launch_bounds__(256) void k_fill_csr(const int* __restrict__ ei, int E,
                                                  const int* __restrict__ rowptr,
                                                  int* cursor, int* csr) {
    int e = blockIdx.x * 256 + threadIdx.x;
    if (e >= E) return;
    int src = ei[e];
    int dst = ei[E + e];
    int p = rowptr[dst] + atomicAdd(&cursor[dst], 1);
    csr[p] = src;
}

__global__ __launch_bounds__(256) void k_f2h(const float* __restrict__ x, __half* __restrict__ y,
                                             int n4) {
    int i = blockIdx.x * 256 + threadIdx.x;
    if (i >= n4) return;
    float4 v = ((const float4*)x)[i];
    __half h[4] = {__float2half_rn(v.x), __float2half_rn(v.y), __float2half_rn(v.z),
                   __float2half_rn(v.w)};
    ((uint2*)y)[i] = *(uint2*)h;
}

// W[K x FO] fp32 -> Wt[FO x K] fp16 (tiny)
__global__ __launch_bounds__(256) void k_wt(const float* __restrict__ W, __half* __restrict__ Wt,
                                            int K, int FO) {
    int i = blockIdx.x * 256 + threadIdx.x;
    if (i >= K * FO) return;
    int k = i / FO;
    int c = i - k * FO;
    Wt[(size_t)c * K + k] = __float2half_rn(W[i]);
}

__device__ inline void unpack8(uint4 v, float* f) {
    __half2* h = (__half2*)&v;
#pragma unroll
    for (int i = 0; i < 4; ++i) {
        float2 t = __half22float2(h[i]);
        f[2 * i] = t.x;
        f[2 * i + 1] = t.y;
    }
}

// CSR gather over 128-wide fp16 rows -> fp16 out (fp32 accum).
// 16 lanes/node, 16B per lane, 4-edge unroll.
__global__ __launch_bounds__(256) void k_gather128(const int* __restrict__ rowptr,
                                                   const int* __restrict__ csr,
                                                   const float* __restrict__ dinv,
                                                   const __half* __restrict__ xh,
                                                   __half* __restrict__ G, int N) {
    int t = blockIdx.x * 256 + threadIdx.x;
    int node = t >> 4;
    if (node >= N) return;
    int lane = t & 15;
    const uint4* xb = (const uint4*)xh;  // 16 uint4 per row
    float di = dinv[node];
    float acc[8];
    {
        uint4 v = xb[(size_t)node * 16 + lane];
        float f[8];
        unpack8(v, f);
        float s = di * di;
#pragma unroll
        for (int j = 0; j < 8; ++j) acc[j] = s * f[j];
    }
    int p0 = rowptr[node], p1 = rowptr[node + 1];
    int p = p0;
    for (; p + 4 <= p1; p += 4) {
        int s0 = csr[p], s1 = csr[p + 1], s2 = csr[p + 2], s3 = csr[p + 3];
        float w0 = di * dinv[s0], w1 = di * dinv[s1], w2 = di * dinv[s2], w3 = di * dinv[s3];
        uint4 v0 = xb[(size_t)s0 * 16 + lane];
        uint4 v1 = xb[(size_t)s1 * 16 + lane];
        uint4 v2 = xb[(size_t)s2 * 16 + lane];
        uint4 v3 = xb[(size_t)s3 * 16 + lane];
        float f0[8], f1[8], f2[8], f3[8];
        unpack8(v0, f0);
        unpack8(v1, f1);
        unpack8(v2, f2);
        unpack8(v3, f3);
#pragma unroll
        for (int j = 0; j < 8; ++j)
            acc[j] += w0 * f0[j] + w1 * f1[j] + w2 * f2[j] + w3 * f3[j];
    }
    for (; p < p1; ++p) {
        int src = csr[p];
        float w = di * dinv[src];
        uint4 v = xb[(size_t)src * 16 + lane];
        float f[8];
        unpack8(v, f);
#pragma unroll
        for (int j = 0; j < 8; ++j) acc[j] += w * f[j];
    }
    __half hh[8];
#pragma unroll
    for (int j = 0; j < 8; ++j) hh[j] = __float2half_rn(acc[j]);
    *(uint4*)&G[(size_t)node * 128 + lane * 8] = *(uint4*)hh;
}

// ---------------------------------------------------------------------------
// MFMA fp16 GEMM, fused epilogue (BN+ReLU or bias+ReLU).
// Block: 256 thr = 4 waves. Tile: 128 rows x 64 cols; wave = 32 rows x 64 cols.
// A[N x K] fp16 row-major (global, 64B/row coalesced); Wt[FO x K] fp16.
// B staged in LDS in MFMA fragment order (lane-linear 16B -> conflict-free).
// mfma_f32_16x16x32_f16: A row=lane&15,k=(lane>>4)*8+j ; B col=lane&15,same k;
// C/D col=lane&15,row=(lane>>4)*4+reg  [HW-verified m89/m91].
// ---------------------------------------------------------------------------
template <int K, bool BN, typename OT>
__global__ __launch_bounds__(256) void k_mfma(const __half* __restrict__ A,
                                              const __half* __restrict__ Wt,
                                              const float* __restrict__ cb,  // conv bias / lin bias
                                              const float* __restrict__ g,
                                              const float* __restrict__ bb,
                                              const float* __restrict__ m,
                                              const float* __restrict__ vv,
                                              OT* __restrict__ Y, int ldy, int N) {
    constexpr int KS = K / 32;   // K-steps
    constexpr int NCT = 4;       // col tiles (64 cols)
    __shared__ __half bs[KS * NCT * 64 * 8];

    const int tid = threadIdx.x;
    const int col0 = blockIdx.y * 64;

    // stage B fragments: piece p = (ks,ct,l) -> 16B at Wt[col][kg..kg+7]
    constexpr int PIECES = KS * NCT * 64;
#pragma unroll
    for (int p = tid; p < PIECES; p += 256) {
        int ks = p / (NCT * 64);
        int rem = p - ks * (NCT * 64);
        int ct = rem >> 6;
        int l = rem & 63;
        int col = col0 + ct * 16 + (l & 15);
        int kg = ks * 32 + (l >> 4) * 8;
        *(uint4*)&bs[p * 8] = *(const uint4*)&Wt[(size_t)col * K + kg];
    }
    __syncthreads();

    const int wave = tid >> 6;
    const int lane = tid & 63;
    const int rbase = blockIdx.x * 128 + wave * 32;
    const int r0 = rbase + (lane & 15);
    const int k0 = (lane >> 4) * 8;

    // preload all A fragments (2 row-tiles x KS)
    uint4 af[2][KS];
#pragma unroll
    for (int ks = 0; ks < KS; ++ks) {
        int kk = ks * 32 + k0;
        af[0][ks] = (r0 < N) ? *(const uint4*)&A[(size_t)r0 * K + kk] : uint4{0, 0, 0, 0};
        af[1][ks] = (r0 + 16 < N) ? *(const uint4*)&A[(size_t)(r0 + 16) * K + kk]
                                  : uint4{0, 0, 0, 0};
    }

    f32x4 acc[2][NCT];
#pragma unroll
    for (int rt = 0; rt < 2; ++rt)
#pragma unroll
        for (int ct = 0; ct < NCT; ++ct) acc[rt][ct] = {0.f, 0.f, 0.f, 0.f};

#pragma unroll
    for (int ks = 0; ks < KS; ++ks) {
        f16x8 b[NCT];
#pragma unroll
        for (int ct = 0; ct < NCT; ++ct)
            b[ct] = *(const f16x8*)&bs[((ks * NCT + ct) * 64 + lane) * 8];
#pragma unroll
        for (int rt = 0; rt < 2; ++rt) {
            f16x8 a = *(const f16x8*)&af[rt][ks];
#pragma unroll
            for (int ct = 0; ct < NCT; ++ct)
                acc[rt][ct] = __builtin_amdgcn_mfma_f32_16x16x32_f16(a, b[ct], acc[rt][ct], 0, 0, 0);
        }
    }

    // epilogue
    const int cbase = col0 + (lane & 15);
#pragma unroll
    for (int ct = 0; ct < NCT; ++ct) {
        int col = cbase + ct * 16;
        float sc, sh;
        if (BN) {
            sc = g[col] * rsqrtf(vv[col] + 1e-5f);
            sh = bb[col] + (cb[col] - m[col]) * sc;
        } else {
            sc = 1.f;
            sh = cb[col];
        }
#pragma unroll
        for (int rt = 0; rt < 2; ++rt) {
#pragma unroll
            for (int r = 0; r < 4; ++r) {
                int row = rbase + rt * 16 + (lane >> 4) * 4 + r;
                if (row < N) {
                    float o = fmaxf(acc[rt][ct][r] * sc + sh, 0.f);
                    if constexpr (sizeof(OT) == 2) {
                        Y[(size_t)row * ldy + col] = __float2half_rn(o);
                    } else {
                        Y[(size_t)row * ldy + col] = o;
                    }
                }
            }
        }
    }
}

// lin2: Y[N x 40] = X[N x 128] @ W[128 x 40] + b  (fp32)
__global__ __launch_bounds__(256) void k_lin2(const float* __restrict__ X,
                                              const float* __restrict__ W,
                                              const float* __restrict__ b,
                                              float* __restrict__ Y, int N) {
    __shared__ float ws[128 * 40];
    __shared__ float xs[4][128];
    const int tid = threadIdx.x;
    const int row0 = blockIdx.x * 4;
#pragma unroll
    for (int idx = tid; idx < 128 * 40 / 4; idx += 256) {
        *(float4*)&ws[idx * 4] = *(const float4*)&W[idx * 4];
    }
    if (tid < 128) {
        int r = tid >> 5;
        int k4 = tid & 31;
        int row = row0 + r;
        float4 v = float4{0.f, 0.f, 0.f, 0.f};
        if (row < N) v = *(const float4*)&X[(size_t)row * 128 + k4 * 4];
        *(float4*)&xs[r][k4 * 4] = v;
    }
    __syncthreads();
    const int tc = tid & 63;
    const int tr = tid >> 6;
    if (tc < 40) {
        float acc = 0.f;
#pragma unroll
        for (int k = 0; k < 128; ++k) acc += xs[tr][k] * ws[k * 40 + tc];
        int row = row0 + tr;
        if (row < N) Y[(size_t)row * 40 + tc] = acc + b[tc];
    }
}

extern "C" void kernel_launch(void* const* d_in, const int* in_sizes, int n_in,
                              void* d_out, int out_size, void* d_ws, size_t ws_size,
                              hipStream_t stream) {
    const float* x = (const float*)d_in[0];
    const int* ei = (const int*)d_in[1];
    const float* cw1 = (const float*)d_in[2];
    const float* cb1 = (const float*)d_in[3];
    const float* g1 = (const float*)d_in[4];
    const float* bb1 = (const float*)d_in[5];
    const float* m1 = (const float*)d_in[6];
    const float* v1 = (const float*)d_in[7];
    const float* cw2 = (const float*)d_in[8];
    const float* cb2 = (const float*)d_in[9];
    const float* g2 = (const float*)d_in[10];
    const float* bb2 = (const float*)d_in[11];
    const float* m2 = (const float*)d_in[12];
    const float* v2 = (const float*)d_in[13];
    const float* cw3 = (const float*)d_in[14];
    const float* cb3 = (const float*)d_in[15];
    const float* g3 = (const float*)d_in[16];
    const float* bb3 = (const float*)d_in[17];
    const float* m3 = (const float*)d_in[18];
    const float* v3 = (const float*)d_in[19];
    const float* lw1 = (const float*)d_in[20];
    const float* lb1 = (const float*)d_in[21];
    const float* lw2 = (const float*)d_in[22];
    const float* lb2 = (const float*)d_in[23];
    float* out = (float*)d_out;

    const int N = in_sizes[0] / 128;
    const int E = in_sizes[1] / 2;

    auto al = [](size_t v) { return (v + 255) & ~(size_t)255; };
    char* w = (char*)d_ws;
    size_t o = 0;
    float* dinv  = (float*)(w + o);  o = al(o + (size_t)N * 4);
    int* deg     = (int*)(w + o);    o = al(o + (size_t)N * 4);   // reused as cursor
    int* rowptr  = (int*)(w + o);    o = al(o + (size_t)(N + 1) * 4);
    int* part    = (int*)(w + o);    o = al(o + 1024 * 4);
    int* csr     = (int*)(w + o);    o = al(o + (size_t)E * 4);
    __half* XH   = (__half*)(w + o); o = al(o + (size_t)N * 128 * 2);
    __half* GH   = (__half*)(w + o); o = al(o + (size_t)N * 128 * 2);
    __half* H3h  = (__half*)(w + o); o = al(o + (size_t)N * 256 * 2);
    float* Z     = (float*)(w + o);  o = al(o + (size_t)N * 128 * 4);
    __half* Wt1  = (__half*)(w + o); o = al(o + (size_t)128 * 128 * 2);
    __half* Wt2  = (__half*)(w + o); o = al(o + (size_t)128 * 128 * 2);
    __half* Wt3  = (__half*)(w + o); o = al(o + (size_t)128 * 256 * 2);
    __half* Wt4  = (__half*)(w + o); o = al(o + (size_t)256 * 128 * 2);

    const int nb = cdiv(N, 256);

    // ---- CSR build ----
    k_zero_int<<<cdiv(N, 256), 256, 0, stream>>>(deg, N);
    k_deg<<<cdiv(E, 256), 256, 0, stream>>>(ei, E, deg);
    k_dinv<<<cdiv(N, 256), 256, 0, stream>>>(deg, dinv, N);
    k_scan1<<<nb, 256, 0, stream>>>(deg, part, N);
    k_scan2<<<1, 1024, 0, stream>>>(part, nb);
    k_scan3<<<nb, 256, 0, stream>>>(deg, part, rowptr, N);
    k_zero_int<<<cdiv(N, 256), 256, 0, stream>>>(deg, N);  // cursor
    k_fill_csr<<<cdiv(E, 256), 256, 0, stream>>>(ei, E, rowptr, deg, csr);

    // ---- conversions ----
    k_f2h<<<cdiv(N * 32, 256), 256, 0, stream>>>(x, XH, N * 32);
    k_wt<<<cdiv(128 * 128, 256), 256, 0, stream>>>(cw1, Wt1, 128, 128);
    k_wt<<<cdiv(128 * 128, 256), 256, 0, stream>>>(cw2, Wt2, 128, 128);
    k_wt<<<cdiv(128 * 256, 256), 256, 0, stream>>>(cw3, Wt3, 128, 256);
    k_wt<<<cdiv(256 * 128, 256), 256, 0, stream>>>(lw1, Wt4, 256, 128);

    const int gx = cdiv(N, 128);

    // ---- conv1: GH = agg(XH); XH = bnrelu(GH @ W1)
    k_gather128<<<cdiv(N, 16), 256, 0, stream>>>(rowptr, csr, dinv, XH, GH, N);
    k_mfma<128, true, __half><<<dim3(gx, 2), 256, 0, stream>>>(GH, Wt1, cb1, g1, bb1, m1, v1,
                                                               XH, 128, N);
    // ---- conv2
    k_gather128<<<cdiv(N, 16), 256, 0, stream>>>(rowptr, csr, dinv, XH, GH, N);
    k_mfma<128, true, __half><<<dim3(gx, 2), 256, 0, stream>>>(GH, Wt2, cb2, g2, bb2, m2, v2,
                                                               XH, 128, N);
    // ---- conv3 (FO=256)
    k_gather128<<<cdiv(N, 16), 256, 0, stream>>>(rowptr, csr, dinv, XH, GH, N);
    k_mfma<128, true, __half><<<dim3(gx, 4), 256, 0, stream>>>(GH, Wt3, cb3, g3, bb3, m3, v3,
                                                               H3h, 256, N);
    // ---- lin1: Z = relu(H3h @ lw1 + lb1)  (fp32 out)
    k_mfma<256, false, float><<<dim3(gx, 2), 256, 0, stream>>>(H3h, Wt4, lb1, nullptr, nullptr,
                                                               nullptr, nullptr, Z, 128, N);
    // ---- lin2
    k_lin2<<<cdiv(N, 4), 256, 0, stream>>>(Z, lw2, lb2, out, N);
}